// Round 2
// baseline (162.372 us; speedup 1.0000x reference)
//
#include <hip/hip_runtime.h>

// 4-bit comparator: A,B are (N,4) float32 of exact 0.0/1.0 values, col 0 = MSB.
// Soft-boolean algebra reduces exactly to integer compare of packed nibbles.
// Outputs: a_gt_b (N floats) then a_eq_b (N floats), concatenated in d_out.
//
// R1: grid-stride + 4-row batching per iteration for memory-level parallelism.
// 2048 blocks x 256 thr = 524288 threads; N=4M rows -> exactly 8 rows/thread
// (2 batched iterations). Loads stay unit-stride per instruction (row = tid +
// k*stride), stores are contiguous 4B/lane.

__device__ __forceinline__ int pack4(float4 v) {
    return ((v.x != 0.0f) << 3) | ((v.y != 0.0f) << 2) |
           ((v.z != 0.0f) << 1) | (v.w != 0.0f);
}

__global__ __launch_bounds__(256) void cmp4_kernel(const float4* __restrict__ A,
                                                   const float4* __restrict__ B,
                                                   float* __restrict__ out_gt,
                                                   float* __restrict__ out_eq,
                                                   int n) {
    const int stride = gridDim.x * blockDim.x;
    int i = blockIdx.x * blockDim.x + threadIdx.x;

    // main loop: 4 independent row-batches in flight per iteration
    for (; i + 3 * stride < n; i += 4 * stride) {
        const int i0 = i, i1 = i + stride, i2 = i + 2 * stride, i3 = i + 3 * stride;
        float4 a0 = A[i0]; float4 a1 = A[i1]; float4 a2 = A[i2]; float4 a3 = A[i3];
        float4 b0 = B[i0]; float4 b1 = B[i1]; float4 b2 = B[i2]; float4 b3 = B[i3];

        int p0 = pack4(a0), q0 = pack4(b0);
        int p1 = pack4(a1), q1 = pack4(b1);
        int p2 = pack4(a2), q2 = pack4(b2);
        int p3 = pack4(a3), q3 = pack4(b3);

        out_gt[i0] = (p0 > q0) ? 1.0f : 0.0f;
        out_gt[i1] = (p1 > q1) ? 1.0f : 0.0f;
        out_gt[i2] = (p2 > q2) ? 1.0f : 0.0f;
        out_gt[i3] = (p3 > q3) ? 1.0f : 0.0f;
        out_eq[i0] = (p0 == q0) ? 1.0f : 0.0f;
        out_eq[i1] = (p1 == q1) ? 1.0f : 0.0f;
        out_eq[i2] = (p2 == q2) ? 1.0f : 0.0f;
        out_eq[i3] = (p3 == q3) ? 1.0f : 0.0f;
    }
    // tail
    for (; i < n; i += stride) {
        float4 a = A[i]; float4 b = B[i];
        int p = pack4(a), q = pack4(b);
        out_gt[i] = (p > q) ? 1.0f : 0.0f;
        out_eq[i] = (p == q) ? 1.0f : 0.0f;
    }
}

extern "C" void kernel_launch(void* const* d_in, const int* in_sizes, int n_in,
                              void* d_out, int out_size, void* d_ws, size_t ws_size,
                              hipStream_t stream) {
    const float4* A = (const float4*)d_in[0];
    const float4* B = (const float4*)d_in[1];
    float* out = (float*)d_out;
    int n = in_sizes[0] / 4;          // rows
    float* out_gt = out;              // first output, N elements
    float* out_eq = out + n;          // second output, N elements
    const int block = 256;
    int grid = 2048;
    int max_grid = (n + block - 1) / block;
    if (grid > max_grid) grid = max_grid;
    cmp4_kernel<<<grid, block, 0, stream>>>(A, B, out_gt, out_eq, n);
}

// Round 4
// 155.566 us; speedup vs baseline: 1.0437x; 1.0437x over previous
//
#include <hip/hip_runtime.h>

// 4-bit comparator: A,B are (N,4) float32 of exact 0.0/1.0, col 0 = MSB.
// Reduces exactly to integer compare of packed nibbles.
// Outputs: a_gt_b (N floats) then a_eq_b (N floats), concatenated in d_out.
//
// R3 (= R2 with compile fix): every memory instruction is a full 1KB/wave
// dwordx4. Thread t owns rows 4t..4t+3: 8x 16B loads (8KB/wave in flight),
// 2x 16B nontemporal stores (write-only output, skip L2 residency).
// Native ext_vector_type used so __builtin_nontemporal_store accepts it.

typedef float v4f __attribute__((ext_vector_type(4)));

__device__ __forceinline__ int pack4(v4f v) {
    return ((v.x != 0.0f) << 3) | ((v.y != 0.0f) << 2) |
           ((v.z != 0.0f) << 1) | (v.w != 0.0f);
}

__global__ __launch_bounds__(256) void cmp4_kernel(const v4f* __restrict__ A,
                                                   const v4f* __restrict__ B,
                                                   v4f* __restrict__ out_gt,
                                                   v4f* __restrict__ out_eq,
                                                   int nquads) {
    int t = blockIdx.x * blockDim.x + threadIdx.x;
    if (t >= nquads) return;

    const v4f* Ar = A + 4 * (size_t)t;
    const v4f* Br = B + 4 * (size_t)t;
    // 8 independent 16B loads — all in flight together
    v4f a0 = Ar[0], a1 = Ar[1], a2 = Ar[2], a3 = Ar[3];
    v4f b0 = Br[0], b1 = Br[1], b2 = Br[2], b3 = Br[3];

    int p0 = pack4(a0), q0 = pack4(b0);
    int p1 = pack4(a1), q1 = pack4(b1);
    int p2 = pack4(a2), q2 = pack4(b2);
    int p3 = pack4(a3), q3 = pack4(b3);

    v4f g = { p0 > q0 ? 1.0f : 0.0f,
              p1 > q1 ? 1.0f : 0.0f,
              p2 > q2 ? 1.0f : 0.0f,
              p3 > q3 ? 1.0f : 0.0f };
    v4f e = { p0 == q0 ? 1.0f : 0.0f,
              p1 == q1 ? 1.0f : 0.0f,
              p2 == q2 ? 1.0f : 0.0f,
              p3 == q3 ? 1.0f : 0.0f };

    __builtin_nontemporal_store(g, &out_gt[t]);
    __builtin_nontemporal_store(e, &out_eq[t]);
}

extern "C" void kernel_launch(void* const* d_in, const int* in_sizes, int n_in,
                              void* d_out, int out_size, void* d_ws, size_t ws_size,
                              hipStream_t stream) {
    const v4f* A = (const v4f*)d_in[0];
    const v4f* B = (const v4f*)d_in[1];
    float* out = (float*)d_out;
    int n = in_sizes[0] / 4;           // rows
    int nquads = n / 4;                // 4 rows per thread (N=4M -> exact)
    v4f* out_gt = (v4f*)out;                 // first output, N floats
    v4f* out_eq = (v4f*)(out + n);           // second output, N floats
    const int block = 256;
    int grid = (nquads + block - 1) / block; // 4096 blocks at N=4M
    cmp4_kernel<<<grid, block, 0, stream>>>(A, B, out_gt, out_eq, nquads);
}

// Round 5
// 148.058 us; speedup vs baseline: 1.0967x; 1.0507x over previous
//
#include <hip/hip_runtime.h>

// 4-bit comparator: A,B are (N,4) float32 of exact 0.0/1.0, col 0 = MSB.
// Reduces exactly to integer compare of packed nibbles.
// Outputs: a_gt_b (N floats) then a_eq_b (N floats), concatenated in d_out.
//
// R4: back to the best shape (R0: 1 row/thread, 16384 blocks) but with
// nontemporal LOADS as well as stores — every byte this kernel touches is
// single-use, so streaming hints keep L2/L3 from churning against the
// harness's own 300MB/iter restore traffic.

typedef float v4f __attribute__((ext_vector_type(4)));

__device__ __forceinline__ int pack4(v4f v) {
    return ((v.x != 0.0f) << 3) | ((v.y != 0.0f) << 2) |
           ((v.z != 0.0f) << 1) | (v.w != 0.0f);
}

__global__ __launch_bounds__(256) void cmp4_kernel(const v4f* __restrict__ A,
                                                   const v4f* __restrict__ B,
                                                   float* __restrict__ out_gt,
                                                   float* __restrict__ out_eq,
                                                   int n) {
    int i = blockIdx.x * blockDim.x + threadIdx.x;
    if (i >= n) return;
    v4f a = __builtin_nontemporal_load(&A[i]);
    v4f b = __builtin_nontemporal_load(&B[i]);
    int ai = pack4(a);
    int bi = pack4(b);
    __builtin_nontemporal_store((ai > bi) ? 1.0f : 0.0f, &out_gt[i]);
    __builtin_nontemporal_store((ai == bi) ? 1.0f : 0.0f, &out_eq[i]);
}

extern "C" void kernel_launch(void* const* d_in, const int* in_sizes, int n_in,
                              void* d_out, int out_size, void* d_ws, size_t ws_size,
                              hipStream_t stream) {
    const v4f* A = (const v4f*)d_in[0];
    const v4f* B = (const v4f*)d_in[1];
    float* out = (float*)d_out;
    int n = in_sizes[0] / 4;          // rows
    float* out_gt = out;              // first output, N elements
    float* out_eq = out + n;          // second output, N elements
    const int block = 256;
    int grid = (n + block - 1) / block;   // 16384 blocks at N=4M
    cmp4_kernel<<<grid, block, 0, stream>>>(A, B, out_gt, out_eq, n);
}